// Round 10
// baseline (304.180 us; speedup 1.0000x reference)
//
#include <hip/hip_runtime.h>
#include <hip/hip_bf16.h>

typedef unsigned short u16;
typedef __attribute__((ext_vector_type(4))) float f32x4;
typedef __attribute__((ext_vector_type(4))) unsigned int u32x4;
typedef __attribute__((ext_vector_type(4))) unsigned short u16x4;
typedef __attribute__((ext_vector_type(8))) unsigned short u16x8;
typedef __attribute__((ext_vector_type(8))) __bf16 bf16x8;

__device__ inline float u2f(u16 u) {
    union { unsigned int i; float f; } x; x.i = ((unsigned int)u) << 16; return x.f;
}
__device__ inline u16 f2u(float f) {
    __hip_bfloat16 b = __float2bfloat16(f);
    return *reinterpret_cast<u16*>(&b);
}
__device__ inline f32x4 mfma16(bf16x8 a, bf16x8 b, f32x4 c) {
    return __builtin_amdgcn_mfma_f32_16x16x32_bf16(a, b, c, 0, 0, 0);
}
__device__ inline void gload_lds16(const u16* g, u16* l) {
    __builtin_amdgcn_global_load_lds(
        (const __attribute__((address_space(1))) unsigned int*)g,
        (__attribute__((address_space(3))) unsigned int*)l, 16, 0, 0);
}

// ---------------------------------------------------------------------------
// Merged projection GEMMs: one dispatch for all four x@W+b (relu) projections.
// grid (8, 320): y<32 lig->l1v(mode1), y<64 lig->l2t(mode3),
// y<192 prot->p1v(mode1), else prot->p2t(mode3). 128x128 tile, K=128.
// ---------------------------------------------------------------------------
__global__ __launch_bounds__(256)
void proj_kernel(const u16* __restrict__ ligb, const u16* __restrict__ protb,
                 const u16* __restrict__ Wl1t, const u16* __restrict__ Wl2t,
                 const u16* __restrict__ Wp1t, const u16* __restrict__ Wp2t,
                 const float* __restrict__ bl1, const float* __restrict__ bl2,
                 const float* __restrict__ bp1, const float* __restrict__ bp2,
                 u16* __restrict__ l1v, u16* __restrict__ l2tv,
                 u16* __restrict__ p1v, u16* __restrict__ p2tv)
{
    __shared__ __align__(16) u16 As[128 * 64];
    __shared__ __align__(16) u16 Bs[128 * 64];
    const int y = blockIdx.y;
    const u16* A; const u16* B; const float* bias; u16* Out;
    int mode, logL, my;
    if (y < 32)       { A = ligb;  B = Wl1t; bias = bl1; Out = l1v;  mode = 1; logL = 8;  my = y; }
    else if (y < 64)  { A = ligb;  B = Wl2t; bias = bl2; Out = l2tv; mode = 3; logL = 8;  my = y - 32; }
    else if (y < 192) { A = protb; B = Wp1t; bias = bp1; Out = p1v;  mode = 1; logL = 10; my = y - 64; }
    else              { A = protb; B = Wp2t; bias = bp2; Out = p2tv; mode = 3; logL = 10; my = y - 192; }
    const int n0 = blockIdx.x * 128, m0 = my * 128;
    const int tid = threadIdx.x;
    const int w = tid >> 6, lane = tid & 63, q = lane >> 4, li = lane & 15;
    const int wr = w >> 1, wc = w & 1;

    const int srow = tid >> 3;
    const int cg = (tid & 7) ^ (srow & 7);
    const int ldsbase = ((tid >> 6) * 8) * 64;

    f32x4 acc[4][4];
    #pragma unroll
    for (int i = 0; i < 4; i++)
        #pragma unroll
        for (int j = 0; j < 4; j++) acc[i][j] = (f32x4){0.f, 0.f, 0.f, 0.f};

    #pragma unroll
    for (int kt = 0; kt < 128; kt += 64) {
        const u16* Ab = A + (long)m0 * 128 + kt + cg * 8;
        const u16* Bb = B + (long)n0 * 128 + kt + cg * 8;
        #pragma unroll
        for (int c = 0; c < 4; c++) {
            gload_lds16(Ab + (long)(c * 32 + srow) * 128, &As[ldsbase + c * 32 * 64]);
            gload_lds16(Bb + (long)(c * 32 + srow) * 128, &Bs[ldsbase + c * 32 * 64]);
        }
        __syncthreads();
        #pragma unroll
        for (int s = 0; s < 2; s++) {
            const int cp = ((s * 4 + q) ^ (li & 7)) * 8;
            bf16x8 av[4], bv[4];
            #pragma unroll
            for (int i = 0; i < 4; i++)
                av[i] = *(bf16x8*)&As[(wr * 64 + i * 16 + li) * 64 + cp];
            #pragma unroll
            for (int j = 0; j < 4; j++)
                bv[j] = *(bf16x8*)&Bs[(wc * 64 + j * 16 + li) * 64 + cp];
            #pragma unroll
            for (int i = 0; i < 4; i++)
                #pragma unroll
                for (int j = 0; j < 4; j++)
                    acc[i][j] = mfma16(av[i], bv[j], acc[i][j]);
        }
        __syncthreads();
    }

    const int Lm = (1 << logL) - 1;
    #pragma unroll
    for (int i = 0; i < 4; i++) {
        #pragma unroll
        for (int j = 0; j < 4; j++) {
            const int col = n0 + wc * 64 + j * 16 + li;
            const float bvs = bias[col];
            if (mode == 3) {
                const int row0 = m0 + wr * 64 + i * 16 + q * 4;
                long base = ((long)(((row0 >> logL) * 8 + (col >> 7)) * 128
                            + (col & 127)) << logL) + (row0 & Lm);
                u16x4 o;
                #pragma unroll
                for (int r = 0; r < 4; r++)
                    o[r] = f2u(fmaxf(acc[i][j][r] + bvs, 0.f));
                *(u16x4*)(Out + base) = o;
            } else {
                #pragma unroll
                for (int r = 0; r < 4; r++) {
                    const int row = m0 + wr * 64 + i * 16 + q * 4 + r;
                    long addr = ((long)((row >> logL) * 8 + (col >> 7)) << (logL + 7))
                              + ((long)(row & Lm) << 7) + (col & 127);
                    Out[addr] = f2u(fmaxf(acc[i][j][r] + bvs, 0.f));
                }
            }
        }
    }
}

// ---------------------------------------------------------------------------
// Merged AV v2, XCD-grouped, 6 slots per bh: role 0,1 = lig AV halves
// (C[128 l][128 d], K=1024, BK=128 = 2x 64-panels/iter -> 8 iters, 16
// barriers), roles 2..5 = prot AV p-quarters (proven 2-stage transpose).
// LDS = 80 KB POOL carved per role.
// ---------------------------------------------------------------------------
__global__ __launch_bounds__(512)
void av_kernel(const u16* __restrict__ att, const u16* __restrict__ p2t,
               const u16* __restrict__ l2t,
               u16* __restrict__ lig3, u16* __restrict__ prot3)
{
    __shared__ __align__(16) u16 POOL[40960];   // 80 KB
    const int id = blockIdx.x;
    const int slot = id >> 3;
    const int bh = (id & 7) * 16 + slot / 6;
    const int role = slot % 6;
    const int tid = threadIdx.x;
    const int w = tid >> 6, lane = tid & 63, q = lane >> 4, li = lane & 15;

    if (role < 2) {
        // ---------------- lig AV half ----------------
        const int r0 = role * 128;
        const u16* A = att + (long)bh * 262144 + (long)r0 * 1024; // [128 l][1024 p]
        const u16* B = p2t + (long)bh * 131072;                   // [128 d][1024 p]
        u16* Ap = POOL;              // [2 pan][128][64]
        u16* Bp = POOL + 16384;      // [2 pan][128][64]
        const int srow = tid >> 3;                // 0..63
        const int cg = (tid & 7) ^ (srow & 7);
        const int ldsb = (tid >> 6) * 8 * 64;
        const int wr = w >> 1, wc = w & 1;        // wr: 32-row strip, wc: 64-col half

        f32x4 acc[2][4];
        #pragma unroll
        for (int i = 0; i < 2; i++)
            #pragma unroll
            for (int j = 0; j < 4; j++) acc[i][j] = (f32x4){0.f, 0.f, 0.f, 0.f};

        for (int kt = 0; kt < 1024; kt += 128) {
            #pragma unroll
            for (int pan = 0; pan < 2; pan++) {
                const int ko = kt + pan * 64 + cg * 8;
                #pragma unroll
                for (int c = 0; c < 2; c++) {
                    gload_lds16(A + (long)(c * 64 + srow) * 1024 + ko,
                                &Ap[pan * 8192 + c * 64 * 64 + ldsb]);
                    gload_lds16(B + (long)(c * 64 + srow) * 1024 + ko,
                                &Bp[pan * 8192 + c * 64 * 64 + ldsb]);
                }
            }
            __syncthreads();
            #pragma unroll
            for (int s = 0; s < 4; s++) {
                const int pan = s >> 1;
                const int cp = (((s & 1) * 4 + q) ^ (li & 7)) * 8;
                bf16x8 av2[2], bv[4];
                #pragma unroll
                for (int i = 0; i < 2; i++)
                    av2[i] = *(bf16x8*)&Ap[pan * 8192 + (wr * 32 + i * 16 + li) * 64 + cp];
                #pragma unroll
                for (int j = 0; j < 4; j++)
                    bv[j] = *(bf16x8*)&Bp[pan * 8192 + (wc * 64 + j * 16 + li) * 64 + cp];
                #pragma unroll
                for (int i = 0; i < 2; i++)
                    #pragma unroll
                    for (int j = 0; j < 4; j++)
                        acc[i][j] = mfma16(av2[i], bv[j], acc[i][j]);
            }
            __syncthreads();
        }

        const long obase = ((long)(bh >> 3) * 256 + r0) * 1024 + (long)(bh & 7) * 128;
        #pragma unroll
        for (int i = 0; i < 2; i++)
            #pragma unroll
            for (int j = 0; j < 4; j++) {
                const int col = wc * 64 + j * 16 + li;
                #pragma unroll
                for (int r = 0; r < 4; r++) {
                    const int row = wr * 32 + i * 16 + q * 4 + r;
                    lig3[obase + (long)row * 1024 + col] = f2u(acc[i][j][r]);
                }
            }
    } else {
        // ---------------- prot AV (unchanged proven structure) ----------------
        const int m0 = (role - 2) * 256;          // p-offset
        const u16* A = att + (long)bh * 262144;   // [256 l][1024 p]
        const u16* B = l2t + (long)bh * 32768;    // [128 d][256 l]
        u16* As = POOL;              // [256][64] XOR-swizzled
        u16* T  = POOL + 16384;      // [64][256]
        u16* Bs = POOL + 32768;      // [128][64]
        const int wr = w >> 1, wc = w & 1;
        const int w6 = tid >> 6;                  // wave id 0..7
        const int i5 = (tid >> 5) & 1;
        const int srow = tid >> 3;                // 0..63 (B staging)
        const int cg = (tid & 7) ^ (srow & 7);
        const int bldsbase = w6 * 8 * 64;

        f32x4 acc[4][4];
        #pragma unroll
        for (int i = 0; i < 4; i++)
            #pragma unroll
            for (int j = 0; j < 4; j++) acc[i][j] = (f32x4){0.f, 0.f, 0.f, 0.f};

        for (int kt = 0; kt < 256; kt += 64) {
            // stage 1: gload att rows [kt, kt+64) x p [m0, m0+256) -> T[l][p]
            #pragma unroll
            for (int c = 0; c < 4; c++) {
                gload_lds16(A + (long)(kt + w6 * 8 + c * 2 + i5) * 1024
                              + m0 + (tid & 31) * 8,
                            &T[w6 * 2048 + c * 512]);
            }
            // B staging: l2t k-minor via gload + XOR
            #pragma unroll
            for (int c = 0; c < 2; c++)
                gload_lds16(B + (long)(c * 64 + srow) * 256 + kt + cg * 8,
                            &Bs[bldsbase + c * 64 * 64]);
            __syncthreads();

            // stage 2: transpose T -> As (XOR chunk swizzle)
            #pragma unroll
            for (int pass = 0; pass < 4; pass++) {
                const int p = pass * 64 + (tid & 63);
                union { u16 e[8]; u32x4 v; } tmp;
                #pragma unroll
                for (int e = 0; e < 8; e++)
                    tmp.e[e] = T[(w6 * 8 + e) * 256 + p];
                *(u32x4*)&As[p * 64 + ((w6 ^ (p & 7)) * 8)] = tmp.v;
            }
            __syncthreads();

            // stage 3: MFMA (XOR reads, proven conflict-free)
            #pragma unroll
            for (int s = 0; s < 2; s++) {
                const int cp = ((s * 4 + q) ^ (li & 7)) * 8;
                bf16x8 av[4], bv[4];
                #pragma unroll
                for (int i = 0; i < 4; i++)
                    av[i] = *(bf16x8*)&As[(wr * 64 + i * 16 + li) * 64 + cp];
                #pragma unroll
                for (int j = 0; j < 4; j++)
                    bv[j] = *(bf16x8*)&Bs[(wc * 64 + j * 16 + li) * 64 + cp];
                #pragma unroll
                for (int i = 0; i < 4; i++)
                    #pragma unroll
                    for (int j = 0; j < 4; j++)
                        acc[i][j] = mfma16(av[i], bv[j], acc[i][j]);
            }
            __syncthreads();
        }

        const long obase = ((long)(bh >> 3) * 1024 + m0) * 1024 + (long)(bh & 7) * 128;
        #pragma unroll
        for (int i = 0; i < 4; i++)
            #pragma unroll
            for (int j = 0; j < 4; j++) {
                const int col = wc * 64 + j * 16 + li;
                #pragma unroll
                for (int r = 0; r < 4; r++) {
                    const int row = wr * 64 + i * 16 + q * 4 + r;
                    prot3[obase + (long)row * 1024 + col] = f2u(acc[i][j][r]);
                }
            }
    }
}

// ---------------------------------------------------------------------------
// Merged finals v2: out = relu([X, resid] @ Wst^T + bc), K = 1152. 64-row
// tiles -> grid (1, 320) so all 256 CUs get work. 256 thr, 4 waves:
// wr = row-half (32 rows), wc = col-half (64 cols), acc[2][4]. LDS 24 KB.
// ---------------------------------------------------------------------------
__global__ __launch_bounds__(256)
void finals_kernel(const u16* __restrict__ lig3, const u16* __restrict__ ligb,
                   const u16* __restrict__ WstL, const float* __restrict__ bcL,
                   float* __restrict__ out0,
                   const u16* __restrict__ prot3, const u16* __restrict__ protb,
                   const u16* __restrict__ WstP, const float* __restrict__ bcP,
                   float* __restrict__ out1)
{
    __shared__ __align__(16) u16 As[64 * 64];
    __shared__ __align__(16) u16 Bs[128 * 64];
    const int y = blockIdx.y;
    const u16 *A, *A2, *B; const float* bias; float* Out; int my;
    if (y < 64) { A = lig3;  A2 = ligb;  B = WstL; bias = bcL; Out = out0; my = y; }
    else        { A = prot3; A2 = protb; B = WstP; bias = bcP; Out = out1; my = y - 64; }
    const int m0 = my * 64;
    const int tid = threadIdx.x;
    const int w = tid >> 6, lane = tid & 63, q = lane >> 4, li = lane & 15;
    const int wr = w >> 1, wc = w & 1;

    const int srow = tid >> 3;
    const int cg = (tid & 7) ^ (srow & 7);
    const int ldsbase = ((tid >> 6) * 8) * 64;

    f32x4 acc[2][4];
    #pragma unroll
    for (int i = 0; i < 2; i++)
        #pragma unroll
        for (int j = 0; j < 4; j++) acc[i][j] = (f32x4){0.f, 0.f, 0.f, 0.f};

    for (int kt = 0; kt < 1152; kt += 64) {
        const u16* Abase; long lda; int ktA;
        if (kt >= 1024) { Abase = A2; lda = 128; ktA = kt - 1024; }
        else            { Abase = A;  lda = 1024; ktA = kt; }
        const u16* Ab = Abase + (long)m0 * lda + ktA + cg * 8;
        const u16* Bb = B + kt + cg * 8;          // n0 = 0, ld 1152
        #pragma unroll
        for (int c = 0; c < 2; c++)
            gload_lds16(Ab + (long)(c * 32 + srow) * lda,  &As[ldsbase + c * 32 * 64]);
        #pragma unroll
        for (int c = 0; c < 4; c++)
            gload_lds16(Bb + (long)(c * 32 + srow) * 1152, &Bs[ldsbase + c * 32 * 64]);
        __syncthreads();
        #pragma unroll
        for (int s = 0; s < 2; s++) {
            const int cp = ((s * 4 + q) ^ (li & 7)) * 8;
            bf16x8 av[2], bv[4];
            #pragma unroll
            for (int i = 0; i < 2; i++)
                av[i] = *(bf16x8*)&As[(wr * 32 + i * 16 + li) * 64 + cp];
            #pragma unroll
            for (int j = 0; j < 4; j++)
                bv[j] = *(bf16x8*)&Bs[(wc * 64 + j * 16 + li) * 64 + cp];
            #pragma unroll
            for (int i = 0; i < 2; i++)
                #pragma unroll
                for (int j = 0; j < 4; j++)
                    acc[i][j] = mfma16(av[i], bv[j], acc[i][j]);
        }
        __syncthreads();
    }

    #pragma unroll
    for (int i = 0; i < 2; i++)
        #pragma unroll
        for (int j = 0; j < 4; j++) {
            const int col = wc * 64 + j * 16 + li;
            const float bvs = bias[col];
            #pragma unroll
            for (int r = 0; r < 4; r++) {
                const int row = m0 + wr * 32 + i * 16 + q * 4 + r;
                Out[(long)row * 128 + col] = fmaxf(acc[i][j][r] + bvs, 0.f);
            }
        }
}

// ---------------------------------------------------------------------------
// Attention v10: QBLK=16 with NATURAL register allocation (plain
// launch_bounds(512) — no min-waves arg; (512,8)->32 VGPR spilled and
// (512,6)->36 VGPR serialized loads, both regressed; v4 at natural 56 VGPR
// is the proven codegen). S[16][1024] = 32 KB LDS -> if VGPR <= 64 the HW
// runs 4 blocks/CU (wave cap) = 2x v4's occupancy; if VGPR > 64 we fall
// back to exactly v4's 2 blocks/CU — downside bounded.
// Grid 2048 XCD-grouped: id&7 = XCD, 16 consecutive slots share one bh ->
// p1 panel (256 KB) L2-resident. Phase 1 barrier-free (af[4], direct global
// B loads, 4 MFMA/fragment); ONE barrier; phases 2-4: row = tid>>5 owns a
// 1024-wide row via 32 lanes (intra-wave shfl only).
// ---------------------------------------------------------------------------
__global__ __launch_bounds__(512)
void attn_kernel(const u16* __restrict__ l1, const u16* __restrict__ p1,
                 const u16* __restrict__ interb, u16* __restrict__ att)
{
    __shared__ __align__(16) u16 S[16 * 1024];   // 32 KB, swizzled bf16 scores
    const int id = blockIdx.x;
    const int slot = id >> 3;
    const int bh = (id & 7) * 16 + (slot >> 4); // XCD id&7 owns bh block
    const int mt = slot & 15;
    const int b  = bh >> 3;
    const int m0 = mt * 16;
    const int tid = threadIdx.x;
    const float rscale = 0.08838834764831845f; // 1/sqrt(128)

    // ---- phase 1: S = (l1 . p1) * rscale, direct global B loads ----
    {
        const int w = tid >> 6, lane = tid & 63, q = lane >> 4, li = lane & 15;
        bf16x8 af[4];
        const u16* lp = l1 + ((long)bh * 256 + m0 + li) * 128 + q * 8;
        #pragma unroll
        for (int s = 0; s < 4; s++) af[s] = *(const bf16x8*)(lp + s * 32);
        // wave w owns p in [w*128, (w+1)*128)
        const u16* bp0 = p1 + ((long)bh * 1024 + w * 128 + li) * 128 + q * 8;
        #pragma unroll
        for (int pf = 0; pf < 8; pf++) {
            const u16* bp = bp0 + (long)pf * 2048;   // 16 p-rows * 128
            bf16x8 bv[4];
            #pragma unroll
            for (int s = 0; s < 4; s++) bv[s] = *(const bf16x8*)(bp + s * 32);
            f32x4 acc = (f32x4){0.f, 0.f, 0.f, 0.f};
            #pragma unroll
            for (int s = 0; s < 4; s++) acc = mfma16(af[s], bv[s], acc);
            const int col = w * 128 + pf * 16 + li;
            #pragma unroll
            for (int r = 0; r < 4; r++) {
                const int row = q * 4 + r;
                S[(row << 10) + (col ^ ((row >> 2) << 4))] = f2u(acc[r] * rscale);
            }
        }
    }
    __syncthreads();

    // ---- phases 2-4: each row owned by 32 lanes of one wave ----
    const int row = tid >> 5;          // 0..15
    const int lj  = tid & 31;          // column chunk within row
    const int l   = m0 + row;
    const int sw2 = (row >> 2) << 4;
    const u16* ib = interb + ((long)b * 256 + l) * 1024;

    // phase 2: multiply by inter (coalesced bf16x8), write back, row max
    float mx = -1e30f;
    #pragma unroll
    for (int blk = 0; blk < 4; blk++) {
        const int c = blk * 256 + lj * 8;
        u16* sp = &S[(row << 10) + (c ^ sw2)];
        u16x8 s8 = *(u16x8*)sp;
        u16x8 i8 = *(const u16x8*)(ib + c);
        u16x8 o8;
        #pragma unroll
        for (int e = 0; e < 8; e++) {
            float v = u2f(s8[e]) * u2f(i8[e]);
            mx = fmaxf(mx, v);
            o8[e] = f2u(v);
        }
        *(u16x8*)sp = o8;
    }
    #pragma unroll
    for (int d = 1; d < 32; d <<= 1) mx = fmaxf(mx, __shfl_xor(mx, d, 64));

    // phase 3: sum of exp
    float z = 0.f;
    #pragma unroll
    for (int blk = 0; blk < 4; blk++) {
        const int c = blk * 256 + lj * 8;
        u16x8 p8 = *(u16x8*)&S[(row << 10) + (c ^ sw2)];
        #pragma unroll
        for (int e = 0; e < 8; e++) z += __expf(u2f(p8[e]) - mx);
    }
    #pragma unroll
    for (int d = 1; d < 32; d <<= 1) z += __shfl_xor(z, d, 64);
    const float inv = 1.f / z;

    // phase 4: normalize + vectorized store
    u16* op = att + ((long)bh * 256 + l) * 1024;
    #pragma unroll
    for (int blk = 0; blk < 4; blk++) {
        const int c = blk * 256 + lj * 8;
        u16x8 p8 = *(u16x8*)&S[(row << 10) + (c ^ sw2)];
        u16x8 o8;
        #pragma unroll
        for (int e = 0; e < 8; e++)
            o8[e] = f2u(__expf(u2f(p8[e]) - mx) * inv);
        *(u16x8*)(op + c) = o8;
    }
}

// ---------------------------------------------------------------------------
// Fused 8-way transpose + fp32->bf16 convert for weights: dst[C,R] = bf16(src^T)
// ---------------------------------------------------------------------------
struct TPF { const float* src; u16* dst; int R; int C; };
struct TPF8 { TPF t[8]; };

__global__ __launch_bounds__(256)
void cvtw_kernel(TPF8 args)
{
    TPF tp = args.t[blockIdx.z];
    const int c0 = blockIdx.x * 32, r0 = blockIdx.y * 32;
    if (c0 >= tp.C || r0 >= tp.R) return;
    __shared__ u16 tile[32][33];
    const int tx = threadIdx.x & 31, ty = threadIdx.x >> 5;
    #pragma unroll
    for (int i = 0; i < 4; i++)
        tile[ty + i * 8][tx] = f2u(tp.src[(long)(r0 + ty + i * 8) * tp.C + c0 + tx]);
    __syncthreads();
    #pragma unroll
    for (int i = 0; i < 4; i++)
        tp.dst[(long)(c0 + ty + i * 8) * tp.R + r0 + tx] = tile[tx][ty + i * 8];
}

// ---------------------------------------------------------------------------
// Weight-combine: Wst[n][0:1024] = Wout_t[n][0:128] @ Wmid_t; tail = resid W;
// bc[n] = bout[n] + bmid . Wout_t[n][0:128].
// ---------------------------------------------------------------------------
__global__ __launch_bounds__(256)
void wcomb_kernel(const u16* __restrict__ Wm0, const u16* __restrict__ Wo0,
                  const float* __restrict__ bm0, const float* __restrict__ bo0,
                  u16* __restrict__ Wst0, float* __restrict__ bc0,
                  const u16* __restrict__ Wm1, const u16* __restrict__ Wo1,
                  const float* __restrict__ bm1, const float* __restrict__ bo1,
                  u16* __restrict__ Wst1, float* __restrict__ bc1)
{
    const int zz = blockIdx.y;
    const u16* Wm = zz ? Wm1 : Wm0;
    const u16* Wo = zz ? Wo1 : Wo0;
    const float* bmid = zz ? bm1 : bm0;
    const float* bout = zz ? bo1 : bo0;
    u16* Wst = zz ? Wst1 : Wst0;
    float* bc = zz ? bc1 : bc0;
    const int n = blockIdx.x;
    const int tid = threadIdx.x;
    __shared__ float wrow[128];
    if (tid < 128) wrow[tid] = u2f(Wo[n * 256 + tid]);
    __syncthreads();
    for (int k = tid; k < 1024; k += 256) {
        float acc = 0.f;
        #pragma unroll 4
        for (int j = 0; j < 128; j++) acc += wrow[j] * u2f(Wm[(long)j * 1024 + k]);
        Wst[(long)n * 1152 + k] = f2u(acc);
    }
    if (tid < 128) Wst[(long)n * 1152 + 1024 + tid] = Wo[n * 256 + 128 + tid];
    if (tid == 0) {
        float acc = bout[n];
        for (int j = 0; j < 128; j++) acc += bmid[j] * wrow[j];
        bc[n] = acc;
    }
}

// ---------------------------------------------------------------------------
// fp32 -> bf16 converts: z=0 ligand, z=1 prot, z=2 inter
// ---------------------------------------------------------------------------
__global__ __launch_bounds__(256)
void cvt3_kernel(const float* __restrict__ a, u16* __restrict__ da, int na,
                 const float* __restrict__ b, u16* __restrict__ db, int nb,
                 const float* __restrict__ c, u16* __restrict__ dc, int nc)
{
    const int zz = blockIdx.y;
    const float* s = zz == 0 ? a : (zz == 1 ? b : c);
    u16* d = zz == 0 ? da : (zz == 1 ? db : dc);
    const int n = zz == 0 ? na : (zz == 1 ? nb : nc);
    const int i = (blockIdx.x * 256 + threadIdx.x) * 4;
    if (i >= n) return;
    const float4 v = *(const float4*)(s + i);
    u16x4 o;
    o.x = f2u(v.x); o.y = f2u(v.y); o.z = f2u(v.z); o.w = f2u(v.w);
    *(u16x4*)(d + i) = o;
}

// ---------------------------------------------------------------------------
extern "C" void kernel_launch(void* const* d_in, const int* in_sizes, int n_in,
                              void* d_out, int out_size, void* d_ws, size_t ws_size,
                              hipStream_t stream)
{
    (void)in_sizes; (void)n_in; (void)out_size; (void)ws_size;
    const float* ligand = (const float*)d_in[0];
    const float* prot   = (const float*)d_in[1];
    const float* inter  = (const float*)d_in[2];
    const float* Wl1 = (const float*)d_in[3];  const float* bl1 = (const float*)d_in[4];
    const float* Wl2 = (const float*)d_in[5];  const float* bl2 = (const float*)d_in[6];
    const float* Wp1 = (const float*)d_in[7];  const float* bp1 = (const float*)d_in[8];
    const float* Wp2 = (const float*)d_in[9];  const float* bp2 = (const float*)d_in[10];
    const float* W11 = (const float*)d_in[11]; const float* b11 = (const float*)d_in[12];
    const float* W12 = (const float*)d_in[13]; const float* b12 = (const float*)d_in[14];
    const float* W21 = (const float*)d_in[15]; const float* b21 = (const float*)d_in[16];
    const float* W22 = (const float*)d_in[17]; const float* b22 = (const float*)d_in[18];

    float* out0 = (float*)d_out;                    // [16,256,128]
    float* out1 = out0 + (size_t)16 * 256 * 128;    // [16,1024,128]

    u16* ws = (u16*)d_ws;
    size_t off = 0;
    auto alloc = [&](size_t n) { u16* p = ws + off; off += n; return p; };
    u16* ligb  = alloc(524288);    // bf16 ligand [4096,128]
    u16* protb = alloc(2097152);   // bf16 prot  [16384,128]
    u16* l1v   = alloc(4194304);   // [16,8,256,128]
    u16* l2t   = alloc(4194304);   // [16,8,128,256]  (head-T)
    u16* p1v   = alloc(16777216);  // [16,8,1024,128]
    u16* p2t   = alloc(16777216);  // [16,8,128,1024] (head-T)
    u16* attv  = alloc(33554432);  // [16,8,256,1024]
    u16* lig3  = alloc(4194304);   // [16,256,1024]
    u16* prot3 = alloc(16777216);  // [16,1024,1024]
    u16* Wl1t  = alloc(131072);    // [1024,128]
    u16* Wl2t  = alloc(131072);
    u16* Wp1t  = alloc(131072);
    u16* Wp2t  = alloc(131072);
    u16* W11t  = alloc(131072);    // [128,1024] = W11^T
    u16* W21t  = alloc(131072);    // [128,1024] = W21^T
    u16* W12t  = alloc(32768);     // [128,256]  = W12^T
    u16* W22t  = alloc(32768);     // [128,256]  = W22^T
    u16* WstL  = alloc(147456);    // [128,1152] combined lig weight
    u16* WstP  = alloc(147456);    // [128,1152] combined prot weight
    float* bcL = (float*)alloc(256);  // [128] f32
    float* bcP = (float*)alloc(256);  // [128] f32

    // interb aliases lig3: interb is consumed by attn_kernel, which completes
    // before av_kernel writes lig3 (stream-ordered). Sizes match exactly
    // (16*256*1024 u16).
    u16* interb = lig3;

    // input conversion (ligand, prot, inter) -> bf16
    cvt3_kernel<<<dim3(4096, 3), 256, 0, stream>>>(
        ligand, ligb, 524288, prot, protb, 2097152, inter, interb, 4194304);

    TPF8 tp;
    tp.t[0] = {Wl1, Wl1t, 128, 1024};
    tp.t[1] = {Wl2, Wl2t, 128, 1024};
    tp.t[2] = {Wp1, Wp1t, 128, 1024};
    tp.t[3] = {Wp2, Wp2t, 128, 1024};
    tp.t[4] = {W11, W11t, 1024, 128};
    tp.t[5] = {W21, W21t, 1024, 128};
    tp.t[6] = {W12, W12t, 256, 128};
    tp.t[7] = {W22, W22t, 256, 128};
    cvtw_kernel<<<dim3(32, 32, 8), 256, 0, stream>>>(tp);

    // combine W11@W12top / W21@W22top + residual halves + biases
    wcomb_kernel<<<dim3(128, 2), 256, 0, stream>>>(
        W11t, W12t, b11, b12, WstL, bcL,
        W21t, W22t, b21, b22, WstP, bcP);

    // all four projections in one dispatch
    proj_kernel<<<dim3(8, 320), 256, 0, stream>>>(
        ligb, protb, Wl1t, Wl2t, Wp1t, Wp2t,
        bl1, bl2, bp1, bp2, l1v, l2t, p1v, p2t);

    // attention scores + softmax (QBLK=16, natural regalloc, XCD-grouped)
    attn_kernel<<<dim3(2048), 512, 0, stream>>>(l1v, p1v, interb, attv);

    // both AV GEMMs in one dispatch (XCD-grouped, 6 slots/bh: 2 lig halves
    // with BK=128 + 4 prot quarters)
    av_kernel<<<dim3(768), 512, 0, stream>>>(attv, p2t, l2t, lig3, prot3);

    // both fused finals in one dispatch (64-row tiles, 320 blocks)
    finals_kernel<<<dim3(1, 320), 256, 0, stream>>>(
        lig3, ligb, WstL, bcL, out0,
        prot3, protb, WstP, bcP, out1);
}

// Round 11
// 285.489 us; speedup vs baseline: 1.0655x; 1.0655x over previous
//
#include <hip/hip_runtime.h>
#include <hip/hip_bf16.h>

typedef unsigned short u16;
typedef __attribute__((ext_vector_type(4))) float f32x4;
typedef __attribute__((ext_vector_type(4))) unsigned int u32x4;
typedef __attribute__((ext_vector_type(4))) unsigned short u16x4;
typedef __attribute__((ext_vector_type(8))) unsigned short u16x8;
typedef __attribute__((ext_vector_type(8))) __bf16 bf16x8;

__device__ inline float u2f(u16 u) {
    union { unsigned int i; float f; } x; x.i = ((unsigned int)u) << 16; return x.f;
}
__device__ inline u16 f2u(float f) {
    __hip_bfloat16 b = __float2bfloat16(f);
    return *reinterpret_cast<u16*>(&b);
}
__device__ inline f32x4 mfma16(bf16x8 a, bf16x8 b, f32x4 c) {
    return __builtin_amdgcn_mfma_f32_16x16x32_bf16(a, b, c, 0, 0, 0);
}
__device__ inline void gload_lds16(const u16* g, u16* l) {
    __builtin_amdgcn_global_load_lds(
        (const __attribute__((address_space(1))) unsigned int*)g,
        (__attribute__((address_space(3))) unsigned int*)l, 16, 0, 0);
}

// ---------------------------------------------------------------------------
// Merged projection GEMMs: one dispatch for all four x@W+b (relu) projections.
// grid (8, 320): y<32 lig->l1v(mode1), y<64 lig->l2t(mode3),
// y<192 prot->p1v(mode1), else prot->p2t(mode3). 128x128 tile, K=128.
// ---------------------------------------------------------------------------
__global__ __launch_bounds__(256)
void proj_kernel(const u16* __restrict__ ligb, const u16* __restrict__ protb,
                 const u16* __restrict__ Wl1t, const u16* __restrict__ Wl2t,
                 const u16* __restrict__ Wp1t, const u16* __restrict__ Wp2t,
                 const float* __restrict__ bl1, const float* __restrict__ bl2,
                 const float* __restrict__ bp1, const float* __restrict__ bp2,
                 u16* __restrict__ l1v, u16* __restrict__ l2tv,
                 u16* __restrict__ p1v, u16* __restrict__ p2tv)
{
    __shared__ __align__(16) u16 As[128 * 64];
    __shared__ __align__(16) u16 Bs[128 * 64];
    const int y = blockIdx.y;
    const u16* A; const u16* B; const float* bias; u16* Out;
    int mode, logL, my;
    if (y < 32)       { A = ligb;  B = Wl1t; bias = bl1; Out = l1v;  mode = 1; logL = 8;  my = y; }
    else if (y < 64)  { A = ligb;  B = Wl2t; bias = bl2; Out = l2tv; mode = 3; logL = 8;  my = y - 32; }
    else if (y < 192) { A = protb; B = Wp1t; bias = bp1; Out = p1v;  mode = 1; logL = 10; my = y - 64; }
    else              { A = protb; B = Wp2t; bias = bp2; Out = p2tv; mode = 3; logL = 10; my = y - 192; }
    const int n0 = blockIdx.x * 128, m0 = my * 128;
    const int tid = threadIdx.x;
    const int w = tid >> 6, lane = tid & 63, q = lane >> 4, li = lane & 15;
    const int wr = w >> 1, wc = w & 1;

    const int srow = tid >> 3;
    const int cg = (tid & 7) ^ (srow & 7);
    const int ldsbase = ((tid >> 6) * 8) * 64;

    f32x4 acc[4][4];
    #pragma unroll
    for (int i = 0; i < 4; i++)
        #pragma unroll
        for (int j = 0; j < 4; j++) acc[i][j] = (f32x4){0.f, 0.f, 0.f, 0.f};

    #pragma unroll
    for (int kt = 0; kt < 128; kt += 64) {
        const u16* Ab = A + (long)m0 * 128 + kt + cg * 8;
        const u16* Bb = B + (long)n0 * 128 + kt + cg * 8;
        #pragma unroll
        for (int c = 0; c < 4; c++) {
            gload_lds16(Ab + (long)(c * 32 + srow) * 128, &As[ldsbase + c * 32 * 64]);
            gload_lds16(Bb + (long)(c * 32 + srow) * 128, &Bs[ldsbase + c * 32 * 64]);
        }
        __syncthreads();
        #pragma unroll
        for (int s = 0; s < 2; s++) {
            const int cp = ((s * 4 + q) ^ (li & 7)) * 8;
            bf16x8 av[4], bv[4];
            #pragma unroll
            for (int i = 0; i < 4; i++)
                av[i] = *(bf16x8*)&As[(wr * 64 + i * 16 + li) * 64 + cp];
            #pragma unroll
            for (int j = 0; j < 4; j++)
                bv[j] = *(bf16x8*)&Bs[(wc * 64 + j * 16 + li) * 64 + cp];
            #pragma unroll
            for (int i = 0; i < 4; i++)
                #pragma unroll
                for (int j = 0; j < 4; j++)
                    acc[i][j] = mfma16(av[i], bv[j], acc[i][j]);
        }
        __syncthreads();
    }

    const int Lm = (1 << logL) - 1;
    #pragma unroll
    for (int i = 0; i < 4; i++) {
        #pragma unroll
        for (int j = 0; j < 4; j++) {
            const int col = n0 + wc * 64 + j * 16 + li;
            const float bvs = bias[col];
            if (mode == 3) {
                const int row0 = m0 + wr * 64 + i * 16 + q * 4;
                long base = ((long)(((row0 >> logL) * 8 + (col >> 7)) * 128
                            + (col & 127)) << logL) + (row0 & Lm);
                u16x4 o;
                #pragma unroll
                for (int r = 0; r < 4; r++)
                    o[r] = f2u(fmaxf(acc[i][j][r] + bvs, 0.f));
                *(u16x4*)(Out + base) = o;
            } else {
                #pragma unroll
                for (int r = 0; r < 4; r++) {
                    const int row = m0 + wr * 64 + i * 16 + q * 4 + r;
                    long addr = ((long)((row >> logL) * 8 + (col >> 7)) << (logL + 7))
                              + ((long)(row & Lm) << 7) + (col & 127);
                    Out[addr] = f2u(fmaxf(acc[i][j][r] + bvs, 0.f));
                }
            }
        }
    }
}

// ---------------------------------------------------------------------------
// Merged AV v2, XCD-grouped, 6 slots per bh: role 0,1 = lig AV halves
// (C[128 l][128 d], K=1024, BK=128 = 2x 64-panels/iter -> 8 iters, 16
// barriers), roles 2..5 = prot AV p-quarters (proven 2-stage transpose).
// LDS = 80 KB POOL carved per role.
// ---------------------------------------------------------------------------
__global__ __launch_bounds__(512)
void av_kernel(const u16* __restrict__ att, const u16* __restrict__ p2t,
               const u16* __restrict__ l2t,
               u16* __restrict__ lig3, u16* __restrict__ prot3)
{
    __shared__ __align__(16) u16 POOL[40960];   // 80 KB
    const int id = blockIdx.x;
    const int slot = id >> 3;
    const int bh = (id & 7) * 16 + slot / 6;
    const int role = slot % 6;
    const int tid = threadIdx.x;
    const int w = tid >> 6, lane = tid & 63, q = lane >> 4, li = lane & 15;

    if (role < 2) {
        // ---------------- lig AV half ----------------
        const int r0 = role * 128;
        const u16* A = att + (long)bh * 262144 + (long)r0 * 1024; // [128 l][1024 p]
        const u16* B = p2t + (long)bh * 131072;                   // [128 d][1024 p]
        u16* Ap = POOL;              // [2 pan][128][64]
        u16* Bp = POOL + 16384;      // [2 pan][128][64]
        const int srow = tid >> 3;                // 0..63
        const int cg = (tid & 7) ^ (srow & 7);
        const int ldsb = (tid >> 6) * 8 * 64;
        const int wr = w >> 1, wc = w & 1;        // wr: 32-row strip, wc: 64-col half

        f32x4 acc[2][4];
        #pragma unroll
        for (int i = 0; i < 2; i++)
            #pragma unroll
            for (int j = 0; j < 4; j++) acc[i][j] = (f32x4){0.f, 0.f, 0.f, 0.f};

        for (int kt = 0; kt < 1024; kt += 128) {
            #pragma unroll
            for (int pan = 0; pan < 2; pan++) {
                const int ko = kt + pan * 64 + cg * 8;
                #pragma unroll
                for (int c = 0; c < 2; c++) {
                    gload_lds16(A + (long)(c * 64 + srow) * 1024 + ko,
                                &Ap[pan * 8192 + c * 64 * 64 + ldsb]);
                    gload_lds16(B + (long)(c * 64 + srow) * 1024 + ko,
                                &Bp[pan * 8192 + c * 64 * 64 + ldsb]);
                }
            }
            __syncthreads();
            #pragma unroll
            for (int s = 0; s < 4; s++) {
                const int pan = s >> 1;
                const int cp = (((s & 1) * 4 + q) ^ (li & 7)) * 8;
                bf16x8 av2[2], bv[4];
                #pragma unroll
                for (int i = 0; i < 2; i++)
                    av2[i] = *(bf16x8*)&Ap[pan * 8192 + (wr * 32 + i * 16 + li) * 64 + cp];
                #pragma unroll
                for (int j = 0; j < 4; j++)
                    bv[j] = *(bf16x8*)&Bp[pan * 8192 + (wc * 64 + j * 16 + li) * 64 + cp];
                #pragma unroll
                for (int i = 0; i < 2; i++)
                    #pragma unroll
                    for (int j = 0; j < 4; j++)
                        acc[i][j] = mfma16(av2[i], bv[j], acc[i][j]);
            }
            __syncthreads();
        }

        const long obase = ((long)(bh >> 3) * 256 + r0) * 1024 + (long)(bh & 7) * 128;
        #pragma unroll
        for (int i = 0; i < 2; i++)
            #pragma unroll
            for (int j = 0; j < 4; j++) {
                const int col = wc * 64 + j * 16 + li;
                #pragma unroll
                for (int r = 0; r < 4; r++) {
                    const int row = wr * 32 + i * 16 + q * 4 + r;
                    lig3[obase + (long)row * 1024 + col] = f2u(acc[i][j][r]);
                }
            }
    } else {
        // ---------------- prot AV (unchanged proven structure) ----------------
        const int m0 = (role - 2) * 256;          // p-offset
        const u16* A = att + (long)bh * 262144;   // [256 l][1024 p]
        const u16* B = l2t + (long)bh * 32768;    // [128 d][256 l]
        u16* As = POOL;              // [256][64] XOR-swizzled
        u16* T  = POOL + 16384;      // [64][256]
        u16* Bs = POOL + 32768;      // [128][64]
        const int wr = w >> 1, wc = w & 1;
        const int w6 = tid >> 6;                  // wave id 0..7
        const int i5 = (tid >> 5) & 1;
        const int srow = tid >> 3;                // 0..63 (B staging)
        const int cg = (tid & 7) ^ (srow & 7);
        const int bldsbase = w6 * 8 * 64;

        f32x4 acc[4][4];
        #pragma unroll
        for (int i = 0; i < 4; i++)
            #pragma unroll
            for (int j = 0; j < 4; j++) acc[i][j] = (f32x4){0.f, 0.f, 0.f, 0.f};

        for (int kt = 0; kt < 256; kt += 64) {
            // stage 1: gload att rows [kt, kt+64) x p [m0, m0+256) -> T[l][p]
            #pragma unroll
            for (int c = 0; c < 4; c++) {
                gload_lds16(A + (long)(kt + w6 * 8 + c * 2 + i5) * 1024
                              + m0 + (tid & 31) * 8,
                            &T[w6 * 2048 + c * 512]);
            }
            // B staging: l2t k-minor via gload + XOR
            #pragma unroll
            for (int c = 0; c < 2; c++)
                gload_lds16(B + (long)(c * 64 + srow) * 256 + kt + cg * 8,
                            &Bs[bldsbase + c * 64 * 64]);
            __syncthreads();

            // stage 2: transpose T -> As (XOR chunk swizzle)
            #pragma unroll
            for (int pass = 0; pass < 4; pass++) {
                const int p = pass * 64 + (tid & 63);
                union { u16 e[8]; u32x4 v; } tmp;
                #pragma unroll
                for (int e = 0; e < 8; e++)
                    tmp.e[e] = T[(w6 * 8 + e) * 256 + p];
                *(u32x4*)&As[p * 64 + ((w6 ^ (p & 7)) * 8)] = tmp.v;
            }
            __syncthreads();

            // stage 3: MFMA (XOR reads, proven conflict-free)
            #pragma unroll
            for (int s = 0; s < 2; s++) {
                const int cp = ((s * 4 + q) ^ (li & 7)) * 8;
                bf16x8 av[4], bv[4];
                #pragma unroll
                for (int i = 0; i < 4; i++)
                    av[i] = *(bf16x8*)&As[(wr * 64 + i * 16 + li) * 64 + cp];
                #pragma unroll
                for (int j = 0; j < 4; j++)
                    bv[j] = *(bf16x8*)&Bs[(wc * 64 + j * 16 + li) * 64 + cp];
                #pragma unroll
                for (int i = 0; i < 4; i++)
                    #pragma unroll
                    for (int j = 0; j < 4; j++)
                        acc[i][j] = mfma16(av[i], bv[j], acc[i][j]);
            }
            __syncthreads();
        }

        const long obase = ((long)(bh >> 3) * 1024 + m0) * 1024 + (long)(bh & 7) * 128;
        #pragma unroll
        for (int i = 0; i < 4; i++)
            #pragma unroll
            for (int j = 0; j < 4; j++) {
                const int col = wc * 64 + j * 16 + li;
                #pragma unroll
                for (int r = 0; r < 4; r++) {
                    const int row = wr * 64 + i * 16 + q * 4 + r;
                    prot3[obase + (long)row * 1024 + col] = f2u(acc[i][j][r]);
                }
            }
    }
}

// ---------------------------------------------------------------------------
// Merged finals v3: out = relu([X, resid] @ Wst^T + bc), K = 1152. 32-row
// tiles -> grid (1, 640): 2.5 blocks/CU resident (v2's 320 blocks = 1.25/CU
// was grid-occupancy-bound; 36 barrier drains/block exposed at 4-5 waves/CU).
// 256 thr, 4 waves: wr = 16-row half, wc = 64-col half, acc[4]. LDS 20 KB
// (As 4 KB = one gload round/iter + Bs 16 KB). Proven staging/XOR patterns.
// ---------------------------------------------------------------------------
__global__ __launch_bounds__(256)
void finals_kernel(const u16* __restrict__ lig3, const u16* __restrict__ ligb,
                   const u16* __restrict__ WstL, const float* __restrict__ bcL,
                   float* __restrict__ out0,
                   const u16* __restrict__ prot3, const u16* __restrict__ protb,
                   const u16* __restrict__ WstP, const float* __restrict__ bcP,
                   float* __restrict__ out1)
{
    __shared__ __align__(16) u16 As[32 * 64];
    __shared__ __align__(16) u16 Bs[128 * 64];
    const int y = blockIdx.y;
    const u16 *A, *A2, *B; const float* bias; float* Out; int my;
    if (y < 128) { A = lig3;  A2 = ligb;  B = WstL; bias = bcL; Out = out0; my = y; }
    else         { A = prot3; A2 = protb; B = WstP; bias = bcP; Out = out1; my = y - 128; }
    const int m0 = my * 32;
    const int tid = threadIdx.x;
    const int w = tid >> 6, lane = tid & 63, q = lane >> 4, li = lane & 15;
    const int wr = w >> 1, wc = w & 1;

    const int srow = tid >> 3;              // 0..31
    const int cg = (tid & 7) ^ (srow & 7);
    const int ldsbase = ((tid >> 6) * 8) * 64;

    f32x4 acc[4];
    #pragma unroll
    for (int j = 0; j < 4; j++) acc[j] = (f32x4){0.f, 0.f, 0.f, 0.f};

    for (int kt = 0; kt < 1152; kt += 64) {
        const u16* Abase; long lda; int ktA;
        if (kt >= 1024) { Abase = A2; lda = 128; ktA = kt - 1024; }
        else            { Abase = A;  lda = 1024; ktA = kt; }
        const u16* Ab = Abase + (long)m0 * lda + ktA + cg * 8;
        const u16* Bb = B + kt + cg * 8;          // n0 = 0, ld 1152
        gload_lds16(Ab + (long)srow * lda, &As[ldsbase]);
        #pragma unroll
        for (int c = 0; c < 4; c++)
            gload_lds16(Bb + (long)(c * 32 + srow) * 1152, &Bs[ldsbase + c * 32 * 64]);
        __syncthreads();
        #pragma unroll
        for (int s = 0; s < 2; s++) {
            const int cp = ((s * 4 + q) ^ (li & 7)) * 8;
            bf16x8 av = *(bf16x8*)&As[(wr * 16 + li) * 64 + cp];
            bf16x8 bv[4];
            #pragma unroll
            for (int j = 0; j < 4; j++)
                bv[j] = *(bf16x8*)&Bs[(wc * 64 + j * 16 + li) * 64 + cp];
            #pragma unroll
            for (int j = 0; j < 4; j++)
                acc[j] = mfma16(av, bv[j], acc[j]);
        }
        __syncthreads();
    }

    #pragma unroll
    for (int j = 0; j < 4; j++) {
        const int col = wc * 64 + j * 16 + li;
        const float bvs = bias[col];
        #pragma unroll
        for (int r = 0; r < 4; r++) {
            const int row = m0 + wr * 16 + q * 4 + r;
            Out[(long)row * 128 + col] = fmaxf(acc[j][r] + bvs, 0.f);
        }
    }
}

// ---------------------------------------------------------------------------
// Attention v11 = v8 (QBLK=32, natural 56 VGPR — proven; QBLK=16 compiles to
// 32 VGPR regardless of hints and regresses) + single-exp softmax: phase 3
// writes exp'd values back into S (owner-lanes only, no race), phase 4 just
// scales — saves 64 v_exp + 64 sub/u2f per thread on the serial chain.
// ---------------------------------------------------------------------------
__global__ __launch_bounds__(512, 4)
void attn_kernel(const u16* __restrict__ l1, const u16* __restrict__ p1,
                 const u16* __restrict__ interb, u16* __restrict__ att)
{
    __shared__ __align__(16) u16 S[32 * 1024];   // 64 KB, swizzled bf16 scores
    const int id = blockIdx.x;
    const int bh = (id & 7) * 16 + (id >> 6);    // XCD id&7 owns bh block
    const int mt = (id >> 3) & 7;
    const int b  = bh >> 3;
    const int m0 = mt * 32;
    const int tid = threadIdx.x;
    const float rscale = 0.08838834764831845f; // 1/sqrt(128)

    // ---- phase 1: S = (l1 . p1) * rscale, direct global B loads ----
    {
        const int w = tid >> 6, lane = tid & 63, q = lane >> 4, li = lane & 15;
        bf16x8 af[2][4];
        #pragma unroll
        for (int g = 0; g < 2; g++) {
            const u16* lp = l1 + ((long)bh * 256 + m0 + g * 16 + li) * 128 + q * 8;
            #pragma unroll
            for (int s = 0; s < 4; s++) af[g][s] = *(const bf16x8*)(lp + s * 32);
        }
        // wave w owns p in [w*128, (w+1)*128)
        const u16* bp0 = p1 + ((long)bh * 1024 + w * 128 + li) * 128 + q * 8;
        #pragma unroll
        for (int pf = 0; pf < 8; pf++) {
            const u16* bp = bp0 + (long)pf * 2048;   // 16 p-rows * 128
            bf16x8 bv[4];
            #pragma unroll
            for (int s = 0; s < 4; s++) bv[s] = *(const bf16x8*)(bp + s * 32);
            f32x4 acc0 = (f32x4){0.f, 0.f, 0.f, 0.f};
            f32x4 acc1 = (f32x4){0.f, 0.f, 0.f, 0.f};
            #pragma unroll
            for (int s = 0; s < 4; s++) {
                acc0 = mfma16(af[0][s], bv[s], acc0);
                acc1 = mfma16(af[1][s], bv[s], acc1);
            }
            const int col = w * 128 + pf * 16 + li;
            #pragma unroll
            for (int r = 0; r < 4; r++) {
                const int row0 = q * 4 + r;          // row-group 0
                S[(row0 << 10) + (col ^ ((row0 >> 2) << 4))] = f2u(acc0[r] * rscale);
                const int row1 = 16 + q * 4 + r;     // row-group 1
                S[(row1 << 10) + (col ^ ((row1 >> 2) << 4))] = f2u(acc1[r] * rscale);
            }
        }
    }
    __syncthreads();

    // ---- phases 2-4: each row owned by one 16-lane group ----
    const int row = tid >> 4;          // 0..31
    const int lj  = tid & 15;          // column chunk within row
    const int l   = m0 + row;
    const int sw2 = (row >> 2) << 4;
    const u16* ib = interb + ((long)b * 256 + l) * 1024;

    // phase 2: multiply by inter (coalesced bf16x8), write back, row max
    float mx = -1e30f;
    #pragma unroll
    for (int blk = 0; blk < 8; blk++) {
        const int c = blk * 128 + lj * 8;
        u16* sp = &S[(row << 10) + (c ^ sw2)];
        u16x8 s8 = *(u16x8*)sp;
        u16x8 i8 = *(const u16x8*)(ib + c);
        u16x8 o8;
        #pragma unroll
        for (int e = 0; e < 8; e++) {
            float v = u2f(s8[e]) * u2f(i8[e]);
            mx = fmaxf(mx, v);
            o8[e] = f2u(v);
        }
        *(u16x8*)sp = o8;
    }
    #pragma unroll
    for (int d = 1; d < 16; d <<= 1) mx = fmaxf(mx, __shfl_xor(mx, d, 64));

    // phase 3: exp in place (write back), accumulate sum
    float z = 0.f;
    #pragma unroll
    for (int blk = 0; blk < 8; blk++) {
        const int c = blk * 128 + lj * 8;
        u16* sp = &S[(row << 10) + (c ^ sw2)];
        u16x8 p8 = *(u16x8*)sp;
        u16x8 o8;
        #pragma unroll
        for (int e = 0; e < 8; e++) {
            const float ex = __expf(u2f(p8[e]) - mx);
            z += ex;
            o8[e] = f2u(ex);
        }
        *(u16x8*)sp = o8;
    }
    #pragma unroll
    for (int d = 1; d < 16; d <<= 1) z += __shfl_xor(z, d, 64);
    const float inv = 1.f / z;

    // phase 4: scale + vectorized store (no exp recompute)
    u16* op = att + ((long)bh * 256 + l) * 1024;
    #pragma unroll
    for (int blk = 0; blk < 8; blk++) {
        const int c = blk * 128 + lj * 8;
        u16x8 p8 = *(u16x8*)&S[(row << 10) + (c ^ sw2)];
        u16x8 o8;
        #pragma unroll
        for (int e = 0; e < 8; e++)
            o8[e] = f2u(u2f(p8[e]) * inv);
        *(u16x8*)(op + c) = o8;
    }
}

// ---------------------------------------------------------------------------
// Fused 8-way transpose + fp32->bf16 convert for weights: dst[C,R] = bf16(src^T)
// ---------------------------------------------------------------------------
struct TPF { const float* src; u16* dst; int R; int C; };
struct TPF8 { TPF t[8]; };

__global__ __launch_bounds__(256)
void cvtw_kernel(TPF8 args)
{
    TPF tp = args.t[blockIdx.z];
    const int c0 = blockIdx.x * 32, r0 = blockIdx.y * 32;
    if (c0 >= tp.C || r0 >= tp.R) return;
    __shared__ u16 tile[32][33];
    const int tx = threadIdx.x & 31, ty = threadIdx.x >> 5;
    #pragma unroll
    for (int i = 0; i < 4; i++)
        tile[ty + i * 8][tx] = f2u(tp.src[(long)(r0 + ty + i * 8) * tp.C + c0 + tx]);
    __syncthreads();
    #pragma unroll
    for (int i = 0; i < 4; i++)
        tp.dst[(long)(c0 + ty + i * 8) * tp.R + r0 + tx] = tile[tx][ty + i * 8];
}

// ---------------------------------------------------------------------------
// Weight-combine: Wst[n][0:1024] = Wout_t[n][0:128] @ Wmid_t; tail = resid W;
// bc[n] = bout[n] + bmid . Wout_t[n][0:128].
// ---------------------------------------------------------------------------
__global__ __launch_bounds__(256)
void wcomb_kernel(const u16* __restrict__ Wm0, const u16* __restrict__ Wo0,
                  const float* __restrict__ bm0, const float* __restrict__ bo0,
                  u16* __restrict__ Wst0, float* __restrict__ bc0,
                  const u16* __restrict__ Wm1, const u16* __restrict__ Wo1,
                  const float* __restrict__ bm1, const float* __restrict__ bo1,
                  u16* __restrict__ Wst1, float* __restrict__ bc1)
{
    const int zz = blockIdx.y;
    const u16* Wm = zz ? Wm1 : Wm0;
    const u16* Wo = zz ? Wo1 : Wo0;
    const float* bmid = zz ? bm1 : bm0;
    const float* bout = zz ? bo1 : bo0;
    u16* Wst = zz ? Wst1 : Wst0;
    float* bc = zz ? bc1 : bc0;
    const int n = blockIdx.x;
    const int tid = threadIdx.x;
    __shared__ float wrow[128];
    if (tid < 128) wrow[tid] = u2f(Wo[n * 256 + tid]);
    __syncthreads();
    for (int k = tid; k < 1024; k += 256) {
        float acc = 0.f;
        #pragma unroll 4
        for (int j = 0; j < 128; j++) acc += wrow[j] * u2f(Wm[(long)j * 1024 + k]);
        Wst[(long)n * 1152 + k] = f2u(acc);
    }
    if (tid < 128) Wst[(long)n * 1152 + 1024 + tid] = Wo[n * 256 + 128 + tid];
    if (tid == 0) {
        float acc = bout[n];
        for (int j = 0; j < 128; j++) acc += bmid[j] * wrow[j];
        bc[n] = acc;
    }
}

// ---------------------------------------------------------------------------
// fp32 -> bf16 converts: z=0 ligand, z=1 prot, z=2 inter
// ---------------------------------------------------------------------------
__global__ __launch_bounds__(256)
void cvt3_kernel(const float* __restrict__ a, u16* __restrict__ da, int na,
                 const float* __restrict__ b, u16* __restrict__ db, int nb,
                 const float* __restrict__ c, u16* __restrict__ dc, int nc)
{
    const int zz = blockIdx.y;
    const float* s = zz == 0 ? a : (zz == 1 ? b : c);
    u16* d = zz == 0 ? da : (zz == 1 ? db : dc);
    const int n = zz == 0 ? na : (zz == 1 ? nb : nc);
    const int i = (blockIdx.x * 256 + threadIdx.x) * 4;
    if (i >= n) return;
    const float4 v = *(const float4*)(s + i);
    u16x4 o;
    o.x = f2u(v.x); o.y = f2u(v.y); o.z = f2u(v.z); o.w = f2u(v.w);
    *(u16x4*)(d + i) = o;
}

// ---------------------------------------------------------------------------
extern "C" void kernel_launch(void* const* d_in, const int* in_sizes, int n_in,
                              void* d_out, int out_size, void* d_ws, size_t ws_size,
                              hipStream_t stream)
{
    (void)in_sizes; (void)n_in; (void)out_size; (void)ws_size;
    const float* ligand = (const float*)d_in[0];
    const float* prot   = (const float*)d_in[1];
    const float* inter  = (const float*)d_in[2];
    const float* Wl1 = (const float*)d_in[3];  const float* bl1 = (const float*)d_in[4];
    const float* Wl2 = (const float*)d_in[5];  const float* bl2 = (const float*)d_in[6];
    const float* Wp1 = (const float*)d_in[7];  const float* bp1 = (const float*)d_in[8];
    const float* Wp2 = (const float*)d_in[9];  const float* bp2 = (const float*)d_in[10];
    const float* W11 = (const float*)d_in[11]; const float* b11 = (const float*)d_in[12];
    const float* W12 = (const float*)d_in[13]; const float* b12 = (const float*)d_in[14];
    const float* W21 = (const float*)d_in[15]; const float* b21 = (const float*)d_in[16];
    const float* W22 = (const float*)d_in[17]; const float* b22 = (const float*)d_in[18];

    float* out0 = (float*)d_out;                    // [16,256,128]
    float* out1 = out0 + (size_t)16 * 256 * 128;    // [16,1024,128]

    u16* ws = (u16*)d_ws;
    size_t off = 0;
    auto alloc = [&](size_t n) { u16* p = ws + off; off += n; return p; };
    u16* ligb  = alloc(524288);    // bf16 ligand [4096,128]
    u16* protb = alloc(2097152);   // bf16 prot  [16384,128]
    u16* l1v   = alloc(4194304);   // [16,8,256,128]
    u16* l2t   = alloc(4194304);   // [16,8,128,256]  (head-T)
    u16* p1v   = alloc(16777216);  // [16,8,1024,128]
    u16* p2t   = alloc(16777216);  // [16,8,128,1024] (head-T)
    u16* attv  = alloc(33554432);  // [16,8,256,1024]
    u16* lig3  = alloc(4194304);   // [16,256,1024]
    u16* prot3 = alloc(16777216);  // [16,1024,1024]
    u16* Wl1t  = alloc(131072);    // [1024,128]
    u16* Wl2t  = alloc(131072);
    u16* Wp1t  = alloc(131072);
    u16* Wp2t  = alloc(131072);
    u16* W11t  = alloc(131072);    // [128,1024] = W11^T
    u16* W21t  = alloc(131072);    // [128,1024] = W21^T
    u16* W12t  = alloc(32768);     // [128,256]  = W12^T
    u16* W22t  = alloc(32768);     // [128,256]  = W22^T
    u16* WstL  = alloc(147456);    // [128,1152] combined lig weight
    u16* WstP  = alloc(147456);    // [128,1152] combined prot weight
    float* bcL = (float*)alloc(256);  // [128] f32
    float* bcP = (float*)alloc(256);  // [128] f32

    // interb aliases lig3: interb is consumed by attn_kernel, which completes
    // before av_kernel writes lig3 (stream-ordered). Sizes match exactly
    // (16*256*1024 u16).
    u16* interb = lig3;

    // input conversion (ligand, prot, inter) -> bf16
    cvt3_kernel<<<dim3(4096, 3), 256, 0, stream>>>(
        ligand, ligb, 524288, prot, protb, 2097152, inter, interb, 4194304);

    TPF8 tp;
    tp.t[0] = {Wl1, Wl1t, 128, 1024};
    tp.t[1] = {Wl2, Wl2t, 128, 1024};
    tp.t[2] = {Wp1, Wp1t, 128, 1024};
    tp.t[3] = {Wp2, Wp2t, 128, 1024};
    tp.t[4] = {W11, W11t, 1024, 128};
    tp.t[5] = {W21, W21t, 1024, 128};
    tp.t[6] = {W12, W12t, 256, 128};
    tp.t[7] = {W22, W22t, 256, 128};
    cvtw_kernel<<<dim3(32, 32, 8), 256, 0, stream>>>(tp);

    // combine W11@W12top / W21@W22top + residual halves + biases
    wcomb_kernel<<<dim3(128, 2), 256, 0, stream>>>(
        W11t, W12t, b11, b12, WstL, bcL,
        W21t, W22t, b21, b22, WstP, bcP);

    // all four projections in one dispatch
    proj_kernel<<<dim3(8, 320), 256, 0, stream>>>(
        ligb, protb, Wl1t, Wl2t, Wp1t, Wp2t,
        bl1, bl2, bp1, bp2, l1v, l2t, p1v, p2t);

    // attention scores + softmax (v8 + single-exp softmax)
    attn_kernel<<<dim3(1024), 512, 0, stream>>>(l1v, p1v, interb, attv);

    // both AV GEMMs in one dispatch (XCD-grouped, 6 slots/bh: 2 lig halves
    // with BK=128 + 4 prot quarters)
    av_kernel<<<dim3(768), 512, 0, stream>>>(attv, p2t, l2t, lig3, prot3);

    // both fused finals in one dispatch (32-row tiles, 640 blocks)
    finals_kernel<<<dim3(1, 640), 256, 0, stream>>>(
        lig3, ligb, WstL, bcL, out0,
        prot3, protb, WstP, bcP, out1);
}